// Round 9
// baseline (1985.030 us; speedup 1.0000x reference)
//
#include <hip/hip_runtime.h>
#include <hip/hip_fp16.h>

#define NCLS 64
#define NSLICE 4          // 4 slices x 16 classes; slice state = Nn*32B < 4MB L2
#define ALPHA 0.9f
#define SCAN_BS 256
#define SCAN_CHUNK 1024   // SCAN_BS * 4 items/thread
#define NBUCK 256
#define BSHIFT 9          // bucket = col >> 9 (512 nodes/bucket, Nn <= 131072)
#define BSPAN 512
#define P1_CAP 3200       // max edges per pass-1 block chunk
#define ROWMASK 0x7FFFFFu // low 23 bits = row id (requires Nn < 2^23)

__device__ __forceinline__ float wave_max64(float v) {
    #pragma unroll
    for (int o = 32; o > 0; o >>= 1) v = fmaxf(v, __shfl_xor(v, o, 64));
    return v;
}
__device__ __forceinline__ float wave_sum64(float v) {
    #pragma unroll
    for (int o = 32; o > 0; o >>= 1) v += __shfl_xor(v, o, 64);
    return v;
}

// Deterministic "last write wins": winner[node] = max index i with mask[i]==node.
__global__ void winner_k(const int* __restrict__ mask, int* __restrict__ winner, int L) {
    int i = blockIdx.x * blockDim.x + threadIdx.x;
    if (i < L) atomicMax(&winner[mask[i]], i);
}

// Coarse 256-bucket histogram of col>>BSHIFT via LDS privatization.
__global__ void bcount_k(const int* __restrict__ col, int* __restrict__ bcnt, int E) {
    __shared__ int h[NBUCK];
    int t = threadIdx.x;
    h[t] = 0;
    __syncthreads();
    int stride = gridDim.x * blockDim.x;
    for (int e = blockIdx.x * blockDim.x + t; e < E; e += stride)
        atomicAdd(&h[col[e] >> BSHIFT], 1);
    __syncthreads();
    if (h[t]) atomicAdd(&bcnt[t], h[t]);
}

// Exclusive scan of bucket counts -> bbase[257]; bcur = bbase.
__global__ void bscan_k(const int* __restrict__ bcnt, int* __restrict__ bbase,
                        int* __restrict__ bcur, int E) {
    __shared__ int lds[NBUCK];
    int t = threadIdx.x;
    int v = bcnt[t];
    lds[t] = v;
    __syncthreads();
    for (int o = 1; o < NBUCK; o <<= 1) {
        int x = (t >= o) ? lds[t - o] : 0;
        __syncthreads();
        lds[t] += x;
        __syncthreads();
    }
    int ex = lds[t] - v;
    bbase[t] = ex;
    bcur[t] = ex;
    if (t == NBUCK - 1) bbase[NBUCK] = E;
}

// Pass 1: bin edges into NBUCK coarse buckets; coalesced copy-out via LDS staging.
// Each staged edge is packed: (col & 511) << 23 | row.
__global__ void binpass1_k(const int* __restrict__ row, const int* __restrict__ col,
                           int* __restrict__ bcur, unsigned* __restrict__ bpk,
                           int E, int chunk) {
    __shared__ int hist[NBUCK];
    __shared__ int scn[NBUCK];
    __shared__ int lbase[NBUCK];
    __shared__ int lcur[NBUCK];
    __shared__ unsigned pay[P1_CAP];
    __shared__ unsigned char bkt[P1_CAP];
    int t = threadIdx.x;
    int e0 = blockIdx.x * chunk;
    int e1 = min(e0 + chunk, E);
    if (e0 >= E) return;
    hist[t] = 0;
    __syncthreads();
    for (int e = e0 + t; e < e1; e += 256)
        atomicAdd(&hist[col[e] >> BSHIFT], 1);
    __syncthreads();
    scn[t] = hist[t];
    __syncthreads();
    for (int o = 1; o < 256; o <<= 1) {
        int y = (t >= o) ? scn[t - o] : 0;
        __syncthreads();
        scn[t] += y;
        __syncthreads();
    }
    int cnt = hist[t];
    int lstart = scn[t] - cnt;            // exclusive local start
    int gb = 0;
    if (cnt > 0) gb = atomicAdd(&bcur[t], cnt);
    lbase[t] = gb - lstart;               // LDS slot i of bucket t -> global lbase[t]+i
    lcur[t] = lstart;
    __syncthreads();
    for (int e = e0 + t; e < e1; e += 256) {
        int c = col[e];
        int b = c >> BSHIFT;
        int p = atomicAdd(&lcur[b], 1);
        pay[p] = ((unsigned)(c & (BSPAN - 1)) << 23) | (unsigned)row[e];
        bkt[p] = (unsigned char)b;
    }
    __syncthreads();
    int n = e1 - e0;
    for (int i = t; i < n; i += 256) {
        unsigned w = pay[i];
        int b = bkt[i];
        bpk[lbase[b] + i] = w;
    }
}

// Per-bucket LDS histogram over sorted packed pairs -> deg + dinv.
__global__ void bdeg_k(const int* __restrict__ bbase, const unsigned* __restrict__ bpk,
                       int* __restrict__ deg, float* __restrict__ dinv, int Nn) {
    __shared__ int hist[BSPAN];
    int b = blockIdx.x;
    int nb0 = b * BSPAN;
    if (nb0 >= Nn) return;
    int t = threadIdx.x;
    hist[t] = 0;
    hist[t + 256] = 0;
    __syncthreads();
    int e0 = bbase[b];
    int e1 = bbase[b + 1];
    for (int e = e0 + t; e < e1; e += 256)
        atomicAdd(&hist[bpk[e] >> 23], 1);
    __syncthreads();
    int n0 = nb0 + t;
    if (n0 < Nn) {
        int d = hist[t];
        deg[n0] = d;
        dinv[n0] = (d > 0) ? rsqrtf((float)d) : 0.0f;
    }
    int n1 = nb0 + 256 + t;
    if (n1 < Nn) {
        int d = hist[t + 256];
        deg[n1] = d;
        dinv[n1] = (d > 0) ? rsqrtf((float)d) : 0.0f;
    }
}

// ---- exclusive scan of deg -> rowptr (proven pipeline) ----
__global__ void scan_local_k(const int* __restrict__ deg, int* __restrict__ rowptr,
                             int* __restrict__ bsum, int n) {
    __shared__ int lds[SCAN_BS];
    int base = blockIdx.x * SCAN_CHUNK;
    int t = threadIdx.x;
    int v[4];
    int s = 0;
    #pragma unroll
    for (int k = 0; k < 4; ++k) {
        int i = base + t * 4 + k;
        v[k] = (i < n) ? deg[i] : 0;
        s += v[k];
    }
    lds[t] = s;
    __syncthreads();
    for (int o = 1; o < SCAN_BS; o <<= 1) {
        int x = (t >= o) ? lds[t - o] : 0;
        __syncthreads();
        lds[t] += x;
        __syncthreads();
    }
    int ex = (t > 0) ? lds[t - 1] : 0;
    #pragma unroll
    for (int k = 0; k < 4; ++k) {
        int i = base + t * 4 + k;
        if (i < n) rowptr[i] = ex;
        ex += v[k];
    }
    if (t == SCAN_BS - 1) bsum[blockIdx.x] = lds[t];
}

__global__ void scan_bsum_k(int* __restrict__ bsum, int nb) {
    __shared__ int lds[SCAN_BS];
    int t = threadIdx.x;
    int v = (t < nb) ? bsum[t] : 0;
    lds[t] = v;
    __syncthreads();
    for (int o = 1; o < SCAN_BS; o <<= 1) {
        int x = (t >= o) ? lds[t - o] : 0;
        __syncthreads();
        lds[t] += x;
        __syncthreads();
    }
    if (t < nb) bsum[t] = lds[t] - v;   // exclusive
}

__global__ void scan_add_k(int* __restrict__ rowptr, const int* __restrict__ bsum, int n) {
    int i = blockIdx.x * blockDim.x + threadIdx.x;
    if (i < n) rowptr[i] += bsum[i / SCAN_CHUNK];
}

// Pass 2: one block per bucket; LDS per-node cursors; src writes stay in a ~65KB window.
__global__ void binpass2_k(const int* __restrict__ rowptr, const unsigned* __restrict__ bpk,
                           int* __restrict__ src, int Nn, int E) {
    __shared__ int cur[BSPAN];
    int b = blockIdx.x;
    int nb0 = b * BSPAN;
    if (nb0 >= Nn) return;
    int nb1 = min(nb0 + BSPAN, Nn);
    int t = threadIdx.x;
    for (int i = nb0 + t; i < nb1; i += 256) cur[i - nb0] = rowptr[i];
    __syncthreads();
    int e0 = rowptr[nb0];
    int e1 = (nb1 < Nn) ? rowptr[nb1] : E;
    for (int e = e0 + t; e < e1; e += 256) {
        unsigned w = bpk[e];
        int p = atomicAdd(&cur[w >> 23], 1);
        src[p] = (int)(w & ROWMASK);
    }
}

// Fused softmax + one-hot clamp + res/v init, CLASS-SLICED layout:
// element (n, class l) lives at half index ((l>>4)*Nn + n)*16 + (l&15).
__global__ void init_k(const float* __restrict__ y, const int* __restrict__ winner,
                       const int* __restrict__ ytrue, const float* __restrict__ dinv,
                       __half* __restrict__ res_h, __half* __restrict__ vh, int Nn) {
    int lane = threadIdx.x & 63;
    int wave = (blockIdx.x * blockDim.x + threadIdx.x) >> 6;
    int nwaves = (gridDim.x * blockDim.x) >> 6;
    for (int n = wave; n < Nn; n += nwaves) {
        float v = y[(size_t)n * NCLS + lane];
        float m = wave_max64(v);
        float e = expf(v - m);
        float s = wave_sum64(e);
        float u = e / s;
        int w = winner[n];
        if (w >= 0) u = (lane == ytrue[w]) ? 1.0f : 0.0f;
        size_t idx = ((size_t)(lane >> 4) * Nn + n) * 16 + (lane & 15);
        res_h[idx] = __float2half((1.0f - ALPHA) * u);
        vh[idx] = __float2half(dinv[n] * u);
    }
}

#define GATHER(dst, s) do {                                                      \
    float2 f_ = __half22float2(vslice[(size_t)(s) * 8 + c]);                     \
    dst.x += f_.x; dst.y += f_.y;                                                \
} while (0)

// Fused pull + update, class-sliced: wave w -> (slice cb = w/Nn, node n = w%Nn).
// Slice-major block order => while a slice is in flight, every XCD's gathers hit
// that slice's 3.2MB working set (L2-resident). Lane = (edge-subgroup, half2-slot):
// 8 edges x 32B per gather instruction; 3-stage shfl_xor reduce across subgroups.
__global__ void pull_k(const int* __restrict__ rowptr, const int* __restrict__ deg,
                       const int* __restrict__ src, const float* __restrict__ dinv,
                       const __half2* __restrict__ vin2, const __half2* __restrict__ res2,
                       __half2* __restrict__ vout2, float2* __restrict__ uout2,
                       int Nn, int last) {
    int lane = threadIdx.x & 63;
    int subgrp = lane >> 3;   // 0..7: which edge of the 8-group
    int c = lane & 7;         // 0..7: half2 slot (classes 2c,2c+1 of the slice)
    int w = (blockIdx.x * blockDim.x + threadIdx.x) >> 6;
    int cb = w / Nn;
    int n = w - cb * Nn;
    if (cb >= NSLICE) return;
    const __half2* vslice = vin2 + (size_t)cb * Nn * 8;
    int start = rowptr[n];
    int len = deg[n];
    float2 a0 = make_float2(0.f, 0.f), a1 = make_float2(0.f, 0.f);
    float2 a2 = make_float2(0.f, 0.f), a3 = make_float2(0.f, 0.f);
    for (int base = 0; base < len; base += 64) {
        int m = min(64, len - base);
        int sv = (lane < m) ? __builtin_nontemporal_load(&src[start + base + lane]) : 0;
        int j = 0;
        for (; j + 32 <= m; j += 32) {
            int s0 = __shfl(sv, j      + subgrp, 64);
            int s1 = __shfl(sv, j + 8  + subgrp, 64);
            int s2 = __shfl(sv, j + 16 + subgrp, 64);
            int s3 = __shfl(sv, j + 24 + subgrp, 64);
            GATHER(a0, s0); GATHER(a1, s1); GATHER(a2, s2); GATHER(a3, s3);
        }
        for (; j + 8 <= m; j += 8) {
            int s0 = __shfl(sv, j + subgrp, 64);
            GATHER(a0, s0);
        }
        if (j < m) {
            int s0 = __shfl(sv, j + subgrp, 64);
            if (j + subgrp < m) GATHER(a0, s0);
        }
    }
    float sx = (a0.x + a1.x) + (a2.x + a3.x);
    float sy = (a0.y + a1.y) + (a2.y + a3.y);
    #pragma unroll
    for (int mask = 8; mask <= 32; mask <<= 1) {
        sx += __shfl_xor(sx, mask, 64);
        sy += __shfl_xor(sy, mask, 64);
    }
    float di = dinv[n];
    size_t ridx = ((size_t)cb * Nn + n) * 8 + c;
    unsigned rraw = __builtin_nontemporal_load(
        reinterpret_cast<const unsigned*>(&res2[ridx]));
    union { unsigned u; __half2 h; } cv; cv.u = rraw;
    float2 r = __half22float2(cv.h);
    float u0 = fminf(fmaxf(ALPHA * (di * sx) + r.x, 0.0f), 1.0f);
    float u1 = fminf(fmaxf(ALPHA * (di * sy) + r.y, 0.0f), 1.0f);
    if (subgrp == 0) {
        if (last) {
            union { float2 f; unsigned long long b; } cf; cf.f = make_float2(u0, u1);
            __builtin_nontemporal_store(cf.b,
                reinterpret_cast<unsigned long long*>(&uout2[(size_t)n * 32 + cb * 8 + c]));
        } else {
            __half2 hv = __floats2half2_rn(di * u0, di * u1);
            union { __half2 h; unsigned b; } ch; ch.h = hv;
            __builtin_nontemporal_store(ch.b, reinterpret_cast<unsigned*>(&vout2[ridx]));
        }
    }
}

extern "C" void kernel_launch(void* const* d_in, const int* in_sizes, int n_in,
                              void* d_out, int out_size, void* d_ws, size_t ws_size,
                              hipStream_t stream) {
    const float* y_soft = (const float*)d_in[0];
    const int* y_true  = (const int*)d_in[1];
    const int* mask    = (const int*)d_in[2];
    const int* edge    = (const int*)d_in[3];

    const int NC = in_sizes[0];          // N * C
    const int Nn = NC / NCLS;            // N
    const int L  = in_sizes[1];
    const int E  = in_sizes[3] / 2;

    const int* row = edge;               // source
    const int* col = edge + E;           // target

    float2* uout2 = (float2*)d_out;      // final fp32 output

    // ---- workspace layout (256B-aligned) ----
    char* ws = (char*)d_ws;
    size_t off = 0;
    auto alloc = [&](size_t bytes) { char* p = ws + off; off += (bytes + 255) & ~(size_t)255; return p; };
    // region0: bpk (setup only, E*4) overlaps vhA+vhB (loop only, NC*4)
    size_t reg0 = (size_t)E * 4;
    size_t vh_bytes = (size_t)NC * 2;
    if (2 * vh_bytes > reg0) reg0 = 2 * vh_bytes;
    char* region0 = alloc(reg0);
    unsigned* bpk = (unsigned*)region0;
    __half* vhA   = (__half*)region0;
    __half* vhB   = (__half*)(region0 + vh_bytes);
    __half* res_h = (__half*)alloc((size_t)NC * 2);
    int*   src    = (int*)alloc((size_t)E * 4);
    int*   deg    = (int*)alloc((size_t)Nn * 4);
    int*   rowptr = (int*)alloc((size_t)Nn * 4);
    float* dinv   = (float*)alloc((size_t)Nn * 4);
    int*   winner = (int*)alloc((size_t)Nn * 4);
    int*   bcnt   = (int*)alloc((size_t)NBUCK * 4);
    int*   bbase  = (int*)alloc((size_t)(NBUCK + 1) * 4);
    int*   bcur   = (int*)alloc((size_t)NBUCK * 4);
    int*   bsum   = (int*)alloc((size_t)SCAN_BS * 4);

    const int NB = (Nn + SCAN_CHUNK - 1) / SCAN_CHUNK;
    const int NBK = (Nn + BSPAN - 1) / BSPAN;

    hipMemsetAsync(winner, 0xFF, (size_t)Nn * 4, stream);  // -1
    hipMemsetAsync(bcnt, 0, (size_t)NBUCK * 4, stream);

    winner_k<<<(L + 255) / 256, 256, 0, stream>>>(mask, winner, L);

    // CSR build: coarse counts -> bucket bases -> sort pass 1 -> per-node deg ->
    // scan -> rowptr -> sort pass 2
    bcount_k<<<1024, 256, 0, stream>>>(col, bcnt, E);
    bscan_k<<<1, NBUCK, 0, stream>>>(bcnt, bbase, bcur, E);
    const int chunk = P1_CAP;
    const int nchunks = (E + chunk - 1) / chunk;
    binpass1_k<<<nchunks, 256, 0, stream>>>(row, col, bcur, bpk, E, chunk);
    bdeg_k<<<NBK, 256, 0, stream>>>(bbase, bpk, deg, dinv, Nn);
    scan_local_k<<<NB, SCAN_BS, 0, stream>>>(deg, rowptr, bsum, Nn);
    scan_bsum_k<<<1, SCAN_BS, 0, stream>>>(bsum, NB);
    scan_add_k<<<(Nn + 255) / 256, 256, 0, stream>>>(rowptr, bsum, Nn);
    binpass2_k<<<NBK, 256, 0, stream>>>(rowptr, bpk, src, Nn, E);

    // Initial state (bpk region is dead after binpass2; vhA/vhB take it over)
    init_k<<<2048, 256, 0, stream>>>(y_soft, winner, y_true, dinv, res_h, vhA, Nn);

    // 10 fused pull+update iterations, fp16 ping-pong; last writes fp32 into d_out.
    const long long total_waves = (long long)NSLICE * Nn;
    const int pull_blocks = (int)((total_waves * 64 + 255) / 256);
    for (int it = 0; it < 10; ++it) {
        const __half2* vin2 = (const __half2*)((it & 1) ? vhB : vhA);
        __half2* vout2      = (__half2*)((it & 1) ? vhA : vhB);
        pull_k<<<pull_blocks, 256, 0, stream>>>(rowptr, deg, src, dinv,
                                                vin2, (const __half2*)res_h,
                                                vout2, uout2, Nn, it == 9);
    }
}

// Round 10
// 863.247 us; speedup vs baseline: 2.2995x; 2.2995x over previous
//
#include <hip/hip_runtime.h>
#include <hip/hip_fp16.h>

#define NCLS 64
#define ALPHA 0.9f
#define SCAN_BS 256
#define SCAN_CHUNK 1024   // SCAN_BS * 4 items/thread
#define NBUCK 256
#define BSHIFT 9          // bucket = col >> 9 (512 nodes/bucket, Nn <= 131072)
#define BSPAN 512
#define P1_CAP 3200       // max edges per pass-1 block chunk
#define ROWMASK 0x7FFFFFu // low 23 bits = row id (requires Nn < 2^23)

__device__ __forceinline__ float wave_max64(float v) {
    #pragma unroll
    for (int o = 32; o > 0; o >>= 1) v = fmaxf(v, __shfl_xor(v, o, 64));
    return v;
}
__device__ __forceinline__ float wave_sum64(float v) {
    #pragma unroll
    for (int o = 32; o > 0; o >>= 1) v += __shfl_xor(v, o, 64);
    return v;
}

// Deterministic "last write wins": winner[node] = max index i with mask[i]==node.
__global__ void winner_k(const int* __restrict__ mask, int* __restrict__ winner, int L) {
    int i = blockIdx.x * blockDim.x + threadIdx.x;
    if (i < L) atomicMax(&winner[mask[i]], i);
}

// Coarse 256-bucket histogram of col>>BSHIFT via LDS privatization.
__global__ void bcount_k(const int* __restrict__ col, int* __restrict__ bcnt, int E) {
    __shared__ int h[NBUCK];
    int t = threadIdx.x;
    h[t] = 0;
    __syncthreads();
    int stride = gridDim.x * blockDim.x;
    for (int e = blockIdx.x * blockDim.x + t; e < E; e += stride)
        atomicAdd(&h[col[e] >> BSHIFT], 1);
    __syncthreads();
    if (h[t]) atomicAdd(&bcnt[t], h[t]);
}

// Exclusive scan of bucket counts -> bbase[257]; bcur = bbase.
__global__ void bscan_k(const int* __restrict__ bcnt, int* __restrict__ bbase,
                        int* __restrict__ bcur, int E) {
    __shared__ int lds[NBUCK];
    int t = threadIdx.x;
    int v = bcnt[t];
    lds[t] = v;
    __syncthreads();
    for (int o = 1; o < NBUCK; o <<= 1) {
        int x = (t >= o) ? lds[t - o] : 0;
        __syncthreads();
        lds[t] += x;
        __syncthreads();
    }
    int ex = lds[t] - v;
    bbase[t] = ex;
    bcur[t] = ex;
    if (t == NBUCK - 1) bbase[NBUCK] = E;
}

// Pass 1: bin edges into NBUCK coarse buckets; coalesced copy-out via LDS staging.
// Each staged edge is packed: (col & 511) << 23 | row.
__global__ void binpass1_k(const int* __restrict__ row, const int* __restrict__ col,
                           int* __restrict__ bcur, unsigned* __restrict__ bpk,
                           int E, int chunk) {
    __shared__ int hist[NBUCK];
    __shared__ int scn[NBUCK];
    __shared__ int lbase[NBUCK];
    __shared__ int lcur[NBUCK];
    __shared__ unsigned pay[P1_CAP];
    __shared__ unsigned char bkt[P1_CAP];
    int t = threadIdx.x;
    int e0 = blockIdx.x * chunk;
    int e1 = min(e0 + chunk, E);
    if (e0 >= E) return;
    hist[t] = 0;
    __syncthreads();
    for (int e = e0 + t; e < e1; e += 256)
        atomicAdd(&hist[col[e] >> BSHIFT], 1);
    __syncthreads();
    scn[t] = hist[t];
    __syncthreads();
    for (int o = 1; o < 256; o <<= 1) {
        int y = (t >= o) ? scn[t - o] : 0;
        __syncthreads();
        scn[t] += y;
        __syncthreads();
    }
    int cnt = hist[t];
    int lstart = scn[t] - cnt;            // exclusive local start
    int gb = 0;
    if (cnt > 0) gb = atomicAdd(&bcur[t], cnt);
    lbase[t] = gb - lstart;               // LDS slot i of bucket t -> global lbase[t]+i
    lcur[t] = lstart;
    __syncthreads();
    for (int e = e0 + t; e < e1; e += 256) {
        int c = col[e];
        int b = c >> BSHIFT;
        int p = atomicAdd(&lcur[b], 1);
        pay[p] = ((unsigned)(c & (BSPAN - 1)) << 23) | (unsigned)row[e];
        bkt[p] = (unsigned char)b;
    }
    __syncthreads();
    int n = e1 - e0;
    for (int i = t; i < n; i += 256) {
        unsigned w = pay[i];
        int b = bkt[i];
        bpk[lbase[b] + i] = w;
    }
}

// Per-bucket LDS histogram over sorted packed pairs -> deg + dinv.
__global__ void bdeg_k(const int* __restrict__ bbase, const unsigned* __restrict__ bpk,
                       int* __restrict__ deg, float* __restrict__ dinv, int Nn) {
    __shared__ int hist[BSPAN];
    int b = blockIdx.x;
    int nb0 = b * BSPAN;
    if (nb0 >= Nn) return;
    int t = threadIdx.x;
    hist[t] = 0;
    hist[t + 256] = 0;
    __syncthreads();
    int e0 = bbase[b];
    int e1 = bbase[b + 1];
    for (int e = e0 + t; e < e1; e += 256)
        atomicAdd(&hist[bpk[e] >> 23], 1);
    __syncthreads();
    int n0 = nb0 + t;
    if (n0 < Nn) {
        int d = hist[t];
        deg[n0] = d;
        dinv[n0] = (d > 0) ? rsqrtf((float)d) : 0.0f;
    }
    int n1 = nb0 + 256 + t;
    if (n1 < Nn) {
        int d = hist[t + 256];
        deg[n1] = d;
        dinv[n1] = (d > 0) ? rsqrtf((float)d) : 0.0f;
    }
}

// ---- exclusive scan of deg -> rowptr (proven pipeline) ----
__global__ void scan_local_k(const int* __restrict__ deg, int* __restrict__ rowptr,
                             int* __restrict__ bsum, int n) {
    __shared__ int lds[SCAN_BS];
    int base = blockIdx.x * SCAN_CHUNK;
    int t = threadIdx.x;
    int v[4];
    int s = 0;
    #pragma unroll
    for (int k = 0; k < 4; ++k) {
        int i = base + t * 4 + k;
        v[k] = (i < n) ? deg[i] : 0;
        s += v[k];
    }
    lds[t] = s;
    __syncthreads();
    for (int o = 1; o < SCAN_BS; o <<= 1) {
        int x = (t >= o) ? lds[t - o] : 0;
        __syncthreads();
        lds[t] += x;
        __syncthreads();
    }
    int ex = (t > 0) ? lds[t - 1] : 0;
    #pragma unroll
    for (int k = 0; k < 4; ++k) {
        int i = base + t * 4 + k;
        if (i < n) rowptr[i] = ex;
        ex += v[k];
    }
    if (t == SCAN_BS - 1) bsum[blockIdx.x] = lds[t];
}

__global__ void scan_bsum_k(int* __restrict__ bsum, int nb) {
    __shared__ int lds[SCAN_BS];
    int t = threadIdx.x;
    int v = (t < nb) ? bsum[t] : 0;
    lds[t] = v;
    __syncthreads();
    for (int o = 1; o < SCAN_BS; o <<= 1) {
        int x = (t >= o) ? lds[t - o] : 0;
        __syncthreads();
        lds[t] += x;
        __syncthreads();
    }
    if (t < nb) bsum[t] = lds[t] - v;   // exclusive
}

__global__ void scan_add_k(int* __restrict__ rowptr, const int* __restrict__ bsum, int n) {
    int i = blockIdx.x * blockDim.x + threadIdx.x;
    if (i < n) rowptr[i] += bsum[i / SCAN_CHUNK];
}

// Pass 2: one block per bucket; LDS per-node cursors; src writes stay in a ~65KB window.
__global__ void binpass2_k(const int* __restrict__ rowptr, const unsigned* __restrict__ bpk,
                           int* __restrict__ src, int Nn, int E) {
    __shared__ int cur[BSPAN];
    int b = blockIdx.x;
    int nb0 = b * BSPAN;
    if (nb0 >= Nn) return;
    int nb1 = min(nb0 + BSPAN, Nn);
    int t = threadIdx.x;
    for (int i = nb0 + t; i < nb1; i += 256) cur[i - nb0] = rowptr[i];
    __syncthreads();
    int e0 = rowptr[nb0];
    int e1 = (nb1 < Nn) ? rowptr[nb1] : E;
    for (int e = e0 + t; e < e1; e += 256) {
        unsigned w = bpk[e];
        int p = atomicAdd(&cur[w >> 23], 1);
        src[p] = (int)(w & ROWMASK);
    }
}

// Fused softmax + one-hot clamp + res/v init. One wave per node, lane = class.
__global__ void init_k(const float* __restrict__ y, const int* __restrict__ winner,
                       const int* __restrict__ ytrue, const float* __restrict__ dinv,
                       __half* __restrict__ res_h, __half* __restrict__ vh, int Nn) {
    int lane = threadIdx.x & 63;
    int wave = (blockIdx.x * blockDim.x + threadIdx.x) >> 6;
    int nwaves = (gridDim.x * blockDim.x) >> 6;
    for (int n = wave; n < Nn; n += nwaves) {
        float v = y[(size_t)n * NCLS + lane];
        float m = wave_max64(v);
        float e = expf(v - m);
        float s = wave_sum64(e);
        float u = e / s;
        int w = winner[n];
        if (w >= 0) u = (lane == ytrue[w]) ? 1.0f : 0.0f;
        res_h[(size_t)n * NCLS + lane] = __float2half((1.0f - ALPHA) * u);
        vh[(size_t)n * NCLS + lane] = __float2half(dinv[n] * u);
    }
}

#define GATHER(dst, s) do {                                                      \
    float2 f_ = __half22float2(vin2[(size_t)(s) * 32 + k]);                      \
    dst.x += f_.x; dst.y += f_.y;                                                \
} while (0)

// Fused pull + update, half2 form: one wave per node; lane k<32 handles classes
// {2k,2k+1} from even edges, lanes 32-63 from odd edges (one full 128B line per
// edge per instruction — never shrink the gather granule below a line).
__global__ void pull_k(const int* __restrict__ rowptr, const int* __restrict__ deg,
                       const int* __restrict__ src, const float* __restrict__ dinv,
                       const __half2* __restrict__ vin2, const __half2* __restrict__ res2,
                       __half2* __restrict__ vout2, float2* __restrict__ uout2,
                       int n_nodes, int last) {
    int lane = threadIdx.x & 63;
    int half_id = lane >> 5;
    int k = lane & 31;
    int n = (blockIdx.x * blockDim.x + threadIdx.x) >> 6;
    if (n >= n_nodes) return;
    int start = rowptr[n];
    int len = deg[n];
    float2 a0 = make_float2(0.f, 0.f), a1 = make_float2(0.f, 0.f);
    float2 a2 = make_float2(0.f, 0.f), a3 = make_float2(0.f, 0.f);
    for (int base = 0; base < len; base += 64) {
        int m = min(64, len - base);
        int sv = (lane < m) ? __builtin_nontemporal_load(&src[start + base + lane]) : 0;
        int j = 0;
        for (; j + 8 <= m; j += 8) {
            int s0 = __shfl(sv, j     + half_id, 64);
            int s1 = __shfl(sv, j + 2 + half_id, 64);
            int s2 = __shfl(sv, j + 4 + half_id, 64);
            int s3 = __shfl(sv, j + 6 + half_id, 64);
            GATHER(a0, s0); GATHER(a1, s1); GATHER(a2, s2); GATHER(a3, s3);
        }
        for (; j + 2 <= m; j += 2) {
            int s0 = __shfl(sv, j + half_id, 64);
            GATHER(a0, s0);
        }
        if (j < m) {
            int s0 = __shfl(sv, j, 64);
            if (half_id == 0) GATHER(a0, s0);
        }
    }
    float sx = (a0.x + a1.x) + (a2.x + a3.x);
    float sy = (a0.y + a1.y) + (a2.y + a3.y);
    sx += __shfl_xor(sx, 32, 64);
    sy += __shfl_xor(sy, 32, 64);
    float di = dinv[n];
    unsigned rraw = __builtin_nontemporal_load(
        reinterpret_cast<const unsigned*>(&res2[(size_t)n * 32 + k]));
    union { unsigned u; __half2 h; } cv; cv.u = rraw;
    float2 r = __half22float2(cv.h);
    float u0 = fminf(fmaxf(ALPHA * (di * sx) + r.x, 0.0f), 1.0f);
    float u1 = fminf(fmaxf(ALPHA * (di * sy) + r.y, 0.0f), 1.0f);
    if (lane < 32) {
        size_t idx = (size_t)n * 32 + k;
        if (last) uout2[idx] = make_float2(u0, u1);
        else      vout2[idx] = __floats2half2_rn(di * u0, di * u1);
    }
}

extern "C" void kernel_launch(void* const* d_in, const int* in_sizes, int n_in,
                              void* d_out, int out_size, void* d_ws, size_t ws_size,
                              hipStream_t stream) {
    const float* y_soft = (const float*)d_in[0];
    const int* y_true  = (const int*)d_in[1];
    const int* mask    = (const int*)d_in[2];
    const int* edge    = (const int*)d_in[3];

    const int NC = in_sizes[0];          // N * C
    const int Nn = NC / NCLS;            // N
    const int L  = in_sizes[1];
    const int E  = in_sizes[3] / 2;

    const int* row = edge;               // source
    const int* col = edge + E;           // target

    float2* uout2 = (float2*)d_out;      // final fp32 output

    // ---- workspace layout (256B-aligned) ----
    char* ws = (char*)d_ws;
    size_t off = 0;
    auto alloc = [&](size_t bytes) { char* p = ws + off; off += (bytes + 255) & ~(size_t)255; return p; };
    // region0: bpk (setup only, E*4) overlaps vhA+vhB (loop only, NC*4)
    size_t reg0 = (size_t)E * 4;
    size_t vh_bytes = (size_t)NC * 2;
    if (2 * vh_bytes > reg0) reg0 = 2 * vh_bytes;
    char* region0 = alloc(reg0);
    unsigned* bpk = (unsigned*)region0;
    __half* vhA   = (__half*)region0;
    __half* vhB   = (__half*)(region0 + vh_bytes);
    __half* res_h = (__half*)alloc((size_t)NC * 2);
    int*   src    = (int*)alloc((size_t)E * 4);
    int*   deg    = (int*)alloc((size_t)Nn * 4);
    int*   rowptr = (int*)alloc((size_t)Nn * 4);
    float* dinv   = (float*)alloc((size_t)Nn * 4);
    int*   winner = (int*)alloc((size_t)Nn * 4);
    int*   bcnt   = (int*)alloc((size_t)NBUCK * 4);
    int*   bbase  = (int*)alloc((size_t)(NBUCK + 1) * 4);
    int*   bcur   = (int*)alloc((size_t)NBUCK * 4);
    int*   bsum   = (int*)alloc((size_t)SCAN_BS * 4);

    const int NB = (Nn + SCAN_CHUNK - 1) / SCAN_CHUNK;
    const int NBK = (Nn + BSPAN - 1) / BSPAN;

    hipMemsetAsync(winner, 0xFF, (size_t)Nn * 4, stream);  // -1
    hipMemsetAsync(bcnt, 0, (size_t)NBUCK * 4, stream);

    winner_k<<<(L + 255) / 256, 256, 0, stream>>>(mask, winner, L);

    // CSR build: coarse counts -> bucket bases -> sort pass 1 -> per-node deg ->
    // scan -> rowptr -> sort pass 2
    bcount_k<<<1024, 256, 0, stream>>>(col, bcnt, E);
    bscan_k<<<1, NBUCK, 0, stream>>>(bcnt, bbase, bcur, E);
    const int chunk = P1_CAP;
    const int nchunks = (E + chunk - 1) / chunk;
    binpass1_k<<<nchunks, 256, 0, stream>>>(row, col, bcur, bpk, E, chunk);
    bdeg_k<<<NBK, 256, 0, stream>>>(bbase, bpk, deg, dinv, Nn);
    scan_local_k<<<NB, SCAN_BS, 0, stream>>>(deg, rowptr, bsum, Nn);
    scan_bsum_k<<<1, SCAN_BS, 0, stream>>>(bsum, NB);
    scan_add_k<<<(Nn + 255) / 256, 256, 0, stream>>>(rowptr, bsum, Nn);
    binpass2_k<<<NBK, 256, 0, stream>>>(rowptr, bpk, src, Nn, E);

    // Initial state (bpk region is dead after binpass2; vhA/vhB take it over)
    init_k<<<2048, 256, 0, stream>>>(y_soft, winner, y_true, dinv, res_h, vhA, Nn);

    // 10 fused pull+update iterations, fp16 ping-pong; last writes fp32 into d_out.
    const int pull_blocks = (Nn * NCLS + 255) / 256;
    for (int it = 0; it < 10; ++it) {
        const __half2* vin2 = (const __half2*)((it & 1) ? vhB : vhA);
        __half2* vout2      = (__half2*)((it & 1) ? vhA : vhB);
        pull_k<<<pull_blocks, 256, 0, stream>>>(rowptr, deg, src, dinv,
                                                vin2, (const __half2*)res_h,
                                                vout2, uout2, Nn, it == 9);
    }
}